// Round 4
// baseline (448.119 us; speedup 1.0000x reference)
//
#include <hip/hip_runtime.h>
#include <hip/hip_bf16.h>

// Problem constants (fixed by reference setup_inputs)
constexpr int Bn = 128;   // batch
constexpr int Tn = 32;    // timesteps
constexpr int Dn = 6400;  // input dim (K)
constexpr int Hn = 1000;  // hidden  (N)
constexpr int An = 4;     // actions
constexpr int Mn = Bn * Tn;   // 4096 GEMM rows
constexpr int Npad = 1024;    // W rows padded so GEMM needs no N-guards

typedef _Float16 half8 __attribute__((ext_vector_type(8)));
typedef _Float16 half4 __attribute__((ext_vector_type(4)));
typedef float floatx4 __attribute__((ext_vector_type(4)));

// Workspace layout (bytes)
constexpr size_t H1_BYTES = (size_t)Mn * Hn * 4;        // 16,384,000
constexpr size_t XS_BYTES = (size_t)Mn * Dn * 2;        // 52,428,800 (per split)
constexpr size_t WS_BYTES = (size_t)Npad * Dn * 2;      // 13,107,200 (per split)
constexpr size_t WS_NEEDED = H1_BYTES + 2 * XS_BYTES + 2 * WS_BYTES;  // 147,456,000

__device__ __forceinline__ void async16(const void* g, void* l) {
    __builtin_amdgcn_global_load_lds(
        (const __attribute__((address_space(1))) void*)g,
        (__attribute__((address_space(3))) void*)l, 16, 0, 0);
}

// ---------------------------------------------------------------------------
// Pre-pass: split X and W1 into fp16 hi/lo once (bandwidth-bound).
//   hi = f16(v); lo = f16((v - hi) * 4096)   [absmax 0.0 verified r2/r3]
// W1 padded to 1024 rows with zeros -> no N-guards anywhere in the GEMM.
// ---------------------------------------------------------------------------
__global__ __launch_bounds__(256)
void cvt_split(const float* __restrict__ X, const float* __restrict__ W1,
               _Float16* __restrict__ Xh, _Float16* __restrict__ Xl,
               _Float16* __restrict__ Wh, _Float16* __restrict__ Wl)
{
    constexpr size_t nX4 = (size_t)Mn * Dn / 4;    // 6,553,600
    constexpr size_t nW4 = (size_t)Npad * Dn / 4;  // 1,638,400
    const size_t i = (size_t)blockIdx.x * 256 + threadIdx.x;
    if (i < nX4) {
        const float4 v = ((const float4*)X)[i];
        half4 hi, lo;
        hi[0] = (_Float16)v.x; lo[0] = (_Float16)((v.x - (float)hi[0]) * 4096.0f);
        hi[1] = (_Float16)v.y; lo[1] = (_Float16)((v.y - (float)hi[1]) * 4096.0f);
        hi[2] = (_Float16)v.z; lo[2] = (_Float16)((v.z - (float)hi[2]) * 4096.0f);
        hi[3] = (_Float16)v.w; lo[3] = (_Float16)((v.w - (float)hi[3]) * 4096.0f);
        ((half4*)Xh)[i] = hi;
        ((half4*)Xl)[i] = lo;
    } else if (i < nX4 + nW4) {
        const size_t j = i - nX4;
        const size_t row = j / (Dn / 4);
        float4 v = make_float4(0.f, 0.f, 0.f, 0.f);
        if (row < Hn) v = ((const float4*)W1)[j];
        half4 hi, lo;
        hi[0] = (_Float16)v.x; lo[0] = (_Float16)((v.x - (float)hi[0]) * 4096.0f);
        hi[1] = (_Float16)v.y; lo[1] = (_Float16)((v.y - (float)hi[1]) * 4096.0f);
        hi[2] = (_Float16)v.z; lo[2] = (_Float16)((v.z - (float)hi[2]) * 4096.0f);
        hi[3] = (_Float16)v.w; lo[3] = (_Float16)((v.w - (float)hi[3]) * 4096.0f);
        ((half4*)Wh)[j] = hi;
        ((half4*)Wl)[j] = lo;
    }
}

// ---------------------------------------------------------------------------
// GEMM (fast path): H1 = Xsplit @ Wsplit^T + b1 with pre-converted fp16.
// 64x64 tile, BK=64, 256 thr (4 waves, wave-tile 32x32 via 2x2 16x16x32).
// Staging: global_load_lds width=16, unpadded LDS [64][64] with XOR chunk
// swizzle (stored pos = chunk ^ (row&7)) -> bank-uniform ds_read_b128.
// Loads for iter k+1 issued after the read-barrier, overlapping MFMAs of k.
// ---------------------------------------------------------------------------
__global__ __launch_bounds__(256, 4)
void gemm_f16(const _Float16* __restrict__ Xh, const _Float16* __restrict__ Xl,
              const _Float16* __restrict__ Wh, const _Float16* __restrict__ Wl,
              const float* __restrict__ b1, float* __restrict__ H1)
{
    constexpr int K = Dn;
    __shared__ __align__(16) _Float16 Ah[64][64];
    __shared__ __align__(16) _Float16 Al[64][64];
    __shared__ __align__(16) _Float16 Bh[64][64];
    __shared__ __align__(16) _Float16 Bl[64][64];

    const int tid = threadIdx.x;
    const int bm = blockIdx.x * 64;
    const int bn = blockIdx.y * 64;
    const int lane = tid & 63;
    const int wid = tid >> 6;
    const int wm = (wid & 1) * 32;
    const int wn = (wid >> 1) * 32;
    const int fr = lane & 15;
    const int fq = lane >> 4;

    // staging map: each wave stages rows [wid*16, wid*16+16) of all 4 tiles,
    // 2 instructions per tile (8 rows each). lane -> row lr, LDS pos lc,
    // fetches global chunk sw = lc ^ lr (8-half chunks).
    const int w16 = wid * 16;
    const int lr = lane >> 3;
    const int lc = lane & 7;
    const int sw = lc ^ lr;

    const size_t offA0 = (size_t)(bm + w16 + lr) * K + sw * 8;
    const size_t offA1 = offA0 + (size_t)8 * K;
    const size_t offB0 = (size_t)(bn + w16 + lr) * K + sw * 8;
    const size_t offB1 = offB0 + (size_t)8 * K;

    auto issue = [&](int k0) {
        async16(Xh + offA0 + k0, &Ah[w16][0]);
        async16(Xh + offA1 + k0, &Ah[w16 + 8][0]);
        async16(Xl + offA0 + k0, &Al[w16][0]);
        async16(Xl + offA1 + k0, &Al[w16 + 8][0]);
        async16(Wh + offB0 + k0, &Bh[w16][0]);
        async16(Wh + offB1 + k0, &Bh[w16 + 8][0]);
        async16(Wl + offB0 + k0, &Bl[w16][0]);
        async16(Wl + offB1 + k0, &Bl[w16 + 8][0]);
    };

    floatx4 acc0[2][2] = {};
    floatx4 acc1[2][2] = {};

    // fragment read addressing (XOR swizzle): row r, chunk c_k = c*4+fq
    // stored at pos c_k ^ (r&7); r&7 == fr&7 for all tiles used.
    const int p0 = (0 * 4 + fq) ^ (fr & 7);
    const int p1 = (1 * 4 + fq) ^ (fr & 7);
    const int rA0 = wm + fr, rA1 = wm + 16 + fr;
    const int rB0 = wn + fr, rB1 = wn + 16 + fr;

    issue(0);
    for (int k0 = 0; k0 < K; k0 += 64) {
        __syncthreads();   // LDS writes from global_load_lds visible

        half8 ahi[2][2], alo[2][2], bhi[2][2], blo[2][2];   // [c][tile]
#pragma unroll
        for (int c = 0; c < 2; ++c) {
            const int o = (c ? p1 : p0) * 8;
            ahi[c][0] = *(const half8*)&Ah[rA0][o];
            ahi[c][1] = *(const half8*)&Ah[rA1][o];
            alo[c][0] = *(const half8*)&Al[rA0][o];
            alo[c][1] = *(const half8*)&Al[rA1][o];
            bhi[c][0] = *(const half8*)&Bh[rB0][o];
            bhi[c][1] = *(const half8*)&Bh[rB1][o];
            blo[c][0] = *(const half8*)&Bl[rB0][o];
            blo[c][1] = *(const half8*)&Bl[rB1][o];
        }
        __syncthreads();   // all waves finished reading this tile

        if (k0 + 64 < K) issue(k0 + 64);   // overlap next loads with MFMAs

#pragma unroll
        for (int c = 0; c < 2; ++c)
#pragma unroll
            for (int mt = 0; mt < 2; ++mt)
#pragma unroll
                for (int nt = 0; nt < 2; ++nt) {
                    acc0[mt][nt] = __builtin_amdgcn_mfma_f32_16x16x32_f16(ahi[c][mt], bhi[c][nt], acc0[mt][nt], 0, 0, 0);
                    acc1[mt][nt] = __builtin_amdgcn_mfma_f32_16x16x32_f16(ahi[c][mt], blo[c][nt], acc1[mt][nt], 0, 0, 0);
                    acc1[mt][nt] = __builtin_amdgcn_mfma_f32_16x16x32_f16(alo[c][mt], bhi[c][nt], acc1[mt][nt], 0, 0, 0);
                }
    }

    // epilogue: C/D layout col=lane&15, row=fq*4+r (m89/m91-verified)
#pragma unroll
    for (int nt = 0; nt < 2; ++nt) {
        const int n = bn + wn + nt * 16 + fr;
        if (n >= Hn) continue;
        const float bias = b1[n];
#pragma unroll
        for (int mt = 0; mt < 2; ++mt) {
            const int m = bm + wm + mt * 16 + fq * 4;
#pragma unroll
            for (int r = 0; r < 4; ++r)
                H1[(size_t)(m + r) * Hn + n] =
                    acc0[mt][nt][r] + acc1[mt][nt][r] * (1.0f / 4096.0f) + bias;
        }
    }
}

// ---------------------------------------------------------------------------
// GEMM (fallback, round-3 verified): used only if ws_size < WS_NEEDED.
// ---------------------------------------------------------------------------
__global__ __launch_bounds__(256, 4)
void gemm_fb(const float* __restrict__ X, const float* __restrict__ W1,
             const float* __restrict__ b1, float* __restrict__ H1)
{
    constexpr int K = Dn;
    constexpr int LD = 72;
    __shared__ __align__(16) _Float16 As[2][64][LD];
    __shared__ __align__(16) _Float16 Bs[2][64][LD];

    const int tid = threadIdx.x;
    const int bm = blockIdx.x * 64;
    const int bn = blockIdx.y * 64;
    const int lane = tid & 63;
    const int wid = tid >> 6;
    const int wm = (wid & 1) * 32;
    const int wn = (wid >> 1) * 32;
    const int fr = lane & 15;
    const int fq = lane >> 4;

    const int row0 = tid >> 3;
    const int row1 = (tid + 256) >> 3;
    const int k8_0 = (tid & 7) * 8;

    float4 rx[2][2], rw[2][2];
    const float zero4[4] = {0.f, 0.f, 0.f, 0.f};

    auto load_tiles = [&](int k0) {
        rx[0][0] = *(const float4*)(X + (size_t)(bm + row0) * K + k0 + k8_0);
        rx[0][1] = *(const float4*)(X + (size_t)(bm + row0) * K + k0 + k8_0 + 4);
        rx[1][0] = *(const float4*)(X + (size_t)(bm + row1) * K + k0 + k8_0);
        rx[1][1] = *(const float4*)(X + (size_t)(bm + row1) * K + k0 + k8_0 + 4);
        const int n0 = bn + row0, n1 = bn + row1;
        if (n0 < Hn) {
            rw[0][0] = *(const float4*)(W1 + (size_t)n0 * K + k0 + k8_0);
            rw[0][1] = *(const float4*)(W1 + (size_t)n0 * K + k0 + k8_0 + 4);
        } else { rw[0][0] = *(const float4*)zero4; rw[0][1] = *(const float4*)zero4; }
        if (n1 < Hn) {
            rw[1][0] = *(const float4*)(W1 + (size_t)n1 * K + k0 + k8_0);
            rw[1][1] = *(const float4*)(W1 + (size_t)n1 * K + k0 + k8_0 + 4);
        } else { rw[1][0] = *(const float4*)zero4; rw[1][1] = *(const float4*)zero4; }
    };

    load_tiles(0);
    floatx4 acc0[2][2] = {};
    floatx4 acc1[2][2] = {};

    for (int k0 = 0; k0 < K; k0 += 64) {
#pragma unroll
        for (int p = 0; p < 2; ++p) {
            const int row = p ? row1 : row0;
            float v[8];
            *(float4*)&v[0] = rx[p][0]; *(float4*)&v[4] = rx[p][1];
            half8 hi, lo;
#pragma unroll
            for (int j = 0; j < 8; ++j) {
                hi[j] = (_Float16)v[j];
                lo[j] = (_Float16)((v[j] - (float)hi[j]) * 4096.0f);
            }
            *(half8*)&As[0][row][k8_0] = hi;
            *(half8*)&As[1][row][k8_0] = lo;

            *(float4*)&v[0] = rw[p][0]; *(float4*)&v[4] = rw[p][1];
#pragma unroll
            for (int j = 0; j < 8; ++j) {
                hi[j] = (_Float16)v[j];
                lo[j] = (_Float16)((v[j] - (float)hi[j]) * 4096.0f);
            }
            *(half8*)&Bs[0][row][k8_0] = hi;
            *(half8*)&Bs[1][row][k8_0] = lo;
        }
        __syncthreads();
        if (k0 + 64 < K) load_tiles(k0 + 64);

#pragma unroll
        for (int c = 0; c < 2; ++c) {
            half8 ahi[2], alo[2], bhi[2], blo[2];
#pragma unroll
            for (int mt = 0; mt < 2; ++mt) {
                ahi[mt] = *(const half8*)&As[0][wm + mt * 16 + fr][c * 32 + fq * 8];
                alo[mt] = *(const half8*)&As[1][wm + mt * 16 + fr][c * 32 + fq * 8];
            }
#pragma unroll
            for (int nt = 0; nt < 2; ++nt) {
                bhi[nt] = *(const half8*)&Bs[0][wn + nt * 16 + fr][c * 32 + fq * 8];
                blo[nt] = *(const half8*)&Bs[1][wn + nt * 16 + fr][c * 32 + fq * 8];
            }
#pragma unroll
            for (int mt = 0; mt < 2; ++mt)
#pragma unroll
                for (int nt = 0; nt < 2; ++nt) {
                    acc0[mt][nt] = __builtin_amdgcn_mfma_f32_16x16x32_f16(ahi[mt], bhi[nt], acc0[mt][nt], 0, 0, 0);
                    acc1[mt][nt] = __builtin_amdgcn_mfma_f32_16x16x32_f16(ahi[mt], blo[nt], acc1[mt][nt], 0, 0, 0);
                    acc1[mt][nt] = __builtin_amdgcn_mfma_f32_16x16x32_f16(alo[mt], bhi[nt], acc1[mt][nt], 0, 0, 0);
                }
        }
        __syncthreads();
    }

#pragma unroll
    for (int nt = 0; nt < 2; ++nt) {
        const int n = bn + wn + nt * 16 + fr;
        if (n >= Hn) continue;
        const float bias = b1[n];
#pragma unroll
        for (int mt = 0; mt < 2; ++mt) {
            const int m = bm + wm + mt * 16 + fq * 4;
#pragma unroll
            for (int r = 0; r < 4; ++r)
                H1[(size_t)(m + r) * Hn + n] =
                    acc0[mt][nt][r] + acc1[mt][nt][r] * (1.0f / 4096.0f) + bias;
        }
    }
}

// ---------------------------------------------------------------------------
// LIF scan, barrier-light. Layer-1 LIF is independent per neuron: each thread
// computes its 32-step spike mask with zero barriers, then 16 waves reduce
// 2 timesteps each over h, then 4 threads run the trivial mem2 recurrence.
// 3 barriers total (vs 64 in round 3).
// ---------------------------------------------------------------------------
__global__ __launch_bounds__(1024)
void snn_scan(const float* __restrict__ H1, const float* __restrict__ W2,
              const float* __restrict__ b2, float* __restrict__ out)
{
    const int b = blockIdx.x;
    const int tid = threadIdx.x;
    const int lane = tid & 63;
    const int wid = tid >> 6;
    const bool act = (tid < Hn);

    __shared__ float w2s[1024][5];     // stride 5 -> conflict-light scalar reads
    __shared__ unsigned smask[1024];
    __shared__ float h2s[Tn][An];

#pragma unroll
    for (int a = 0; a < An; ++a)
        w2s[tid][a] = act ? W2[a * Hn + tid] : 0.f;

    // phase 1: per-neuron spike mask (no barriers)
    float cur[Tn];
#pragma unroll
    for (int t = 0; t < Tn; ++t)
        cur[t] = act ? H1[((size_t)b * Tn + t) * Hn + tid] : 0.f;

    unsigned mask = 0;
    float mem1 = 0.f;
#pragma unroll
    for (int t = 0; t < Tn; ++t) {
        const float reset = (mem1 > 1.0f) ? 1.0f : 0.0f;
        mem1 = (0.99f * mem1 + cur[t]) * (1.0f - reset);
        if (mem1 > 1.0f) mask |= (1u << t);
    }
    smask[tid] = mask;
    __syncthreads();

    // phase 2: wave w reduces timesteps 2w, 2w+1 over all h
#pragma unroll
    for (int tt = 0; tt < 2; ++tt) {
        const int t = wid * 2 + tt;
        float p[An] = {0.f, 0.f, 0.f, 0.f};
        for (int h = lane; h < 1024; h += 64) {
            const float g = (smask[h] >> t) & 1u ? 1.0f : 0.0f;
#pragma unroll
            for (int a = 0; a < An; ++a) p[a] += g * w2s[h][a];
        }
#pragma unroll
        for (int off = 32; off > 0; off >>= 1)
#pragma unroll
            for (int a = 0; a < An; ++a) p[a] += __shfl_down(p[a], off, 64);
        if (lane == 0) {
#pragma unroll
            for (int a = 0; a < An; ++a) h2s[t][a] = p[a];
        }
    }
    __syncthreads();

    // phase 3: mem2 recurrence (a = tid), write spikes
    if (tid < An) {
        const float bias = b2[tid];
        float mem2 = 0.f;
#pragma unroll
        for (int t = 0; t < Tn; ++t) {
            const float h2 = h2s[t][tid] + bias;
            const float reset = (mem2 > 1.0f) ? 1.0f : 0.0f;
            mem2 = (0.99f * mem2 + h2) * (1.0f - reset);
            out[((size_t)b * Tn + t) * An + tid] = (mem2 > 1.0f) ? 1.0f : 0.0f;
        }
    }
}

extern "C" void kernel_launch(void* const* d_in, const int* in_sizes, int n_in,
                              void* d_out, int out_size, void* d_ws, size_t ws_size,
                              hipStream_t stream) {
    const float* x  = (const float*)d_in[0];   // [B,T,D]
    const float* W1 = (const float*)d_in[1];   // [H,D]
    const float* b1 = (const float*)d_in[2];   // [H]
    const float* W2 = (const float*)d_in[3];   // [A,H]
    const float* b2 = (const float*)d_in[4];   // [A]
    float* out = (float*)d_out;                // [B,T,A]

    char* ws = (char*)d_ws;
    float* H1 = (float*)ws;

    if (ws_size >= WS_NEEDED) {
        _Float16* Xh = (_Float16*)(ws + H1_BYTES);
        _Float16* Xl = (_Float16*)(ws + H1_BYTES + XS_BYTES);
        _Float16* Wh = (_Float16*)(ws + H1_BYTES + 2 * XS_BYTES);
        _Float16* Wl = (_Float16*)(ws + H1_BYTES + 2 * XS_BYTES + WS_BYTES);

        constexpr size_t n4 = ((size_t)Mn * Dn + (size_t)Npad * Dn) / 4;
        cvt_split<<<(unsigned)((n4 + 255) / 256), 256, 0, stream>>>(x, W1, Xh, Xl, Wh, Wl);

        dim3 grid(Mn / 64, Npad / 64);         // 64 x 16 = 1024 blocks
        gemm_f16<<<grid, 256, 0, stream>>>(Xh, Xl, Wh, Wl, b1, H1);
    } else {
        dim3 grid(Mn / 64, (Hn + 63) / 64);
        gemm_fb<<<grid, 256, 0, stream>>>(x, W1, b1, H1);
    }
    snn_scan<<<Bn, 1024, 0, stream>>>(H1, W2, b2, out);
}

// Round 5
// 397.235 us; speedup vs baseline: 1.1281x; 1.1281x over previous
//
#include <hip/hip_runtime.h>
#include <hip/hip_bf16.h>

// Problem constants (fixed by reference setup_inputs)
constexpr int Bn = 128;   // batch
constexpr int Tn = 32;    // timesteps
constexpr int Dn = 6400;  // input dim (K)
constexpr int Hn = 1000;  // hidden  (N)
constexpr int An = 4;     // actions
constexpr int Mn = Bn * Tn;   // 4096 GEMM rows
constexpr int Npad = 1024;    // W rows padded -> no N-guards in GEMM

constexpr int KS = Dn / 32;   // 200 K-chunks of 32
constexpr int MC = Mn / 16;   // 256 m-chunks of 16 rows
constexpr int NC = Npad / 16; // 64  n-chunks of 16 rows

typedef _Float16 half8 __attribute__((ext_vector_type(8)));
typedef float floatx4 __attribute__((ext_vector_type(4)));

// Workspace layout (bytes)
constexpr size_t H1_BYTES  = (size_t)Mn * Hn * 4;
constexpr size_t XS_BYTES  = (size_t)Mn * Dn * 2;       // per split
constexpr size_t WSp_BYTES = (size_t)Npad * Dn * 2;     // per split
constexpr size_t WS_NEEDED = H1_BYTES + 2 * XS_BYTES + 2 * WSp_BYTES;

__device__ __forceinline__ void async16(const void* g, void* l) {
    __builtin_amdgcn_global_load_lds(
        (const __attribute__((address_space(1))) void*)g,
        (__attribute__((address_space(3))) void*)l, 16, 0, 0);
}

// ---------------------------------------------------------------------------
// Pre-pass: fp16 hi/lo split (absmax 0.0 verified r2-r4) AND permute into
// MFMA-fragment order. A 1 KB "frag chunk" (ks, m4) holds 16 rows x 32 k:
// lane l's half8 at byte l*16 covers row m4*16+(l&15), k = ks*32+((l>>4)&3)*8.
// Chunk index: X: c = ks*MC + m4 ; W: c = ks*NC + n4 (rows >= Hn zeroed).
// GEMM then stages with perfectly-coalesced 1 KB global_load_lds and reads
// fragments at lane*16 -- sequential, zero bank conflicts, zero addr VALU.
// ---------------------------------------------------------------------------
__global__ __launch_bounds__(256)
void cvt_frag(const float* __restrict__ X, const float* __restrict__ W1,
              _Float16* __restrict__ Xh, _Float16* __restrict__ Xl,
              _Float16* __restrict__ Wh, _Float16* __restrict__ Wl)
{
    constexpr size_t nX8 = (size_t)Mn * Dn / 8;    // 3,276,800 half8s
    constexpr size_t nW8 = (size_t)Npad * Dn / 8;  //   819,200 half8s
    const size_t i = (size_t)blockIdx.x * 256 + threadIdx.x;

    float v[8];
    if (i < nX8) {
        const int c = (int)(i >> 6), l = (int)(i & 63);
        const int ks = c >> 8, m4 = c & (MC - 1);        // MC=256 pow2
        const int m = m4 * 16 + (l & 15);
        const int k = ks * 32 + ((l >> 4) & 3) * 8;
        const float4 v0 = *(const float4*)(X + (size_t)m * Dn + k);
        const float4 v1 = *(const float4*)(X + (size_t)m * Dn + k + 4);
        *(float4*)&v[0] = v0; *(float4*)&v[4] = v1;
        half8 hi, lo;
#pragma unroll
        for (int j = 0; j < 8; ++j) {
            hi[j] = (_Float16)v[j];
            lo[j] = (_Float16)((v[j] - (float)hi[j]) * 4096.0f);
        }
        *(half8*)(Xh + i * 8) = hi;
        *(half8*)(Xl + i * 8) = lo;
    } else if (i < nX8 + nW8) {
        const size_t jx = i - nX8;
        const int c = (int)(jx >> 6), l = (int)(jx & 63);
        const int ks = c >> 6, n4 = c & (NC - 1);        // NC=64 pow2
        const int n = n4 * 16 + (l & 15);
        const int k = ks * 32 + ((l >> 4) & 3) * 8;
        if (n < Hn) {
            const float4 v0 = *(const float4*)(W1 + (size_t)n * Dn + k);
            const float4 v1 = *(const float4*)(W1 + (size_t)n * Dn + k + 4);
            *(float4*)&v[0] = v0; *(float4*)&v[4] = v1;
        } else {
#pragma unroll
            for (int j = 0; j < 8; ++j) v[j] = 0.f;
        }
        half8 hi, lo;
#pragma unroll
        for (int j = 0; j < 8; ++j) {
            hi[j] = (_Float16)v[j];
            lo[j] = (_Float16)((v[j] - (float)hi[j]) * 4096.0f);
        }
        *(half8*)(Wh + jx * 8) = hi;
        *(half8*)(Wl + jx * 8) = lo;
    }
}

// ---------------------------------------------------------------------------
// GEMM: H1 = X @ W1^T + b1 via fp16-split MFMA on fragment-ordered inputs.
// 128x128 block tile, 256 thr = 4 waves (2x2), wave-tile 64x64 = 4x4 16x16x32
// tiles: 16 ds_read_b128 feed 48 MFMAs per iter (3x better LDS amortization
// than r4's 32x32 wave-tile -- r4 was LDS-BW-bound). Double-buffered LDS
// (2 x 32 KB), one barrier/iter; loads for iter k+1 issued right after the
// barrier, landing during iter k's MFMAs. Grid 256 blocks, n = bid&7 so each
// XCD reuses one W-slab (3.3 MB) from its L2.
// ---------------------------------------------------------------------------
__global__ __launch_bounds__(256, 1)
void gemm_frag(const _Float16* __restrict__ Xh, const _Float16* __restrict__ Xl,
               const _Float16* __restrict__ Wh, const _Float16* __restrict__ Wl,
               const float* __restrict__ b1, float* __restrict__ H1)
{
    __shared__ __align__(16) _Float16 S[2][4][8][512];   // [buf][Ah,Al,Bh,Bl][chunk][1KB] = 64 KB

    const int tid = threadIdx.x;
    const int lane = tid & 63;
    const int w = tid >> 6;
    const int nb = blockIdx.x & 7;
    const int mb = blockIdx.x >> 3;
    const int bm4 = mb * 8;           // base m-chunk (128 rows / 16)
    const int bn4 = nb * 8;
    const int wm = w & 1;
    const int wn = w >> 1;

    auto issue = [&](int ks, int buf) {
#pragma unroll
        for (int r = 0; r < 2; ++r) {
            const int i = w * 2 + r;                     // wave stages chunks 2w,2w+1 of all 4 arrays
            const size_t ga = ((size_t)(ks * MC + bm4 + i)) * 512 + lane * 8;
            const size_t gb = ((size_t)(ks * NC + bn4 + i)) * 512 + lane * 8;
            async16(Xh + ga, &S[buf][0][i][0]);
            async16(Xl + ga, &S[buf][1][i][0]);
            async16(Wh + gb, &S[buf][2][i][0]);
            async16(Wl + gb, &S[buf][3][i][0]);
        }
    };

    floatx4 acc0[4][4] = {};
    floatx4 acc1[4][4] = {};

    issue(0, 0);
    for (int it = 0; it < KS; ++it) {
        const int buf = it & 1;
        __syncthreads();                       // drains vmcnt: buf's chunks landed; buf^1 readers done
        if (it + 1 < KS) issue(it + 1, buf ^ 1);

        half8 ah[4], al[4], bh[4], bl[4];
#pragma unroll
        for (int mt = 0; mt < 4; ++mt) {
            ah[mt] = *(const half8*)&S[buf][0][wm * 4 + mt][lane * 8];
            al[mt] = *(const half8*)&S[buf][1][wm * 4 + mt][lane * 8];
        }
#pragma unroll
        for (int nt = 0; nt < 4; ++nt) {
            bh[nt] = *(const half8*)&S[buf][2][wn * 4 + nt][lane * 8];
            bl[nt] = *(const half8*)&S[buf][3][wn * 4 + nt][lane * 8];
        }
#pragma unroll
        for (int mt = 0; mt < 4; ++mt)
#pragma unroll
            for (int nt = 0; nt < 4; ++nt) {
                acc0[mt][nt] = __builtin_amdgcn_mfma_f32_16x16x32_f16(ah[mt], bh[nt], acc0[mt][nt], 0, 0, 0);
                acc1[mt][nt] = __builtin_amdgcn_mfma_f32_16x16x32_f16(ah[mt], bl[nt], acc1[mt][nt], 0, 0, 0);
                acc1[mt][nt] = __builtin_amdgcn_mfma_f32_16x16x32_f16(al[mt], bh[nt], acc1[mt][nt], 0, 0, 0);
            }
    }

    // epilogue: C/D layout col=lane&15, row=(lane>>4)*4+r (m89/m91-verified)
    const int fr = lane & 15;
    const int fq = lane >> 4;
#pragma unroll
    for (int nt = 0; nt < 4; ++nt) {
        const int n = nb * 128 + wn * 64 + nt * 16 + fr;
        if (n >= Hn) continue;
        const float bias = b1[n];
#pragma unroll
        for (int mt = 0; mt < 4; ++mt) {
            const int m = mb * 128 + wm * 64 + mt * 16 + fq * 4;
#pragma unroll
            for (int r = 0; r < 4; ++r)
                H1[(size_t)(m + r) * Hn + n] =
                    acc0[mt][nt][r] + acc1[mt][nt][r] * (1.0f / 4096.0f) + bias;
        }
    }
}

// ---------------------------------------------------------------------------
// GEMM fallback (round-3 verified): only if ws_size < WS_NEEDED.
// ---------------------------------------------------------------------------
__global__ __launch_bounds__(256, 4)
void gemm_fb(const float* __restrict__ X, const float* __restrict__ W1,
             const float* __restrict__ b1, float* __restrict__ H1)
{
    constexpr int K = Dn;
    constexpr int LD = 72;
    __shared__ __align__(16) _Float16 As[2][64][LD];
    __shared__ __align__(16) _Float16 Bs[2][64][LD];

    const int tid = threadIdx.x;
    const int bm = blockIdx.x * 64;
    const int bn = blockIdx.y * 64;
    const int lane = tid & 63;
    const int wid = tid >> 6;
    const int wm = (wid & 1) * 32;
    const int wn = (wid >> 1) * 32;
    const int fr = lane & 15;
    const int fq = lane >> 4;

    const int row0 = tid >> 3;
    const int row1 = (tid + 256) >> 3;
    const int k8_0 = (tid & 7) * 8;

    float4 rx[2][2], rw[2][2];
    const float zero4[4] = {0.f, 0.f, 0.f, 0.f};

    auto load_tiles = [&](int k0) {
        rx[0][0] = *(const float4*)(X + (size_t)(bm + row0) * K + k0 + k8_0);
        rx[0][1] = *(const float4*)(X + (size_t)(bm + row0) * K + k0 + k8_0 + 4);
        rx[1][0] = *(const float4*)(X + (size_t)(bm + row1) * K + k0 + k8_0);
        rx[1][1] = *(const float4*)(X + (size_t)(bm + row1) * K + k0 + k8_0 + 4);
        const int n0 = bn + row0, n1 = bn + row1;
        if (n0 < Hn) {
            rw[0][0] = *(const float4*)(W1 + (size_t)n0 * K + k0 + k8_0);
            rw[0][1] = *(const float4*)(W1 + (size_t)n0 * K + k0 + k8_0 + 4);
        } else { rw[0][0] = *(const float4*)zero4; rw[0][1] = *(const float4*)zero4; }
        if (n1 < Hn) {
            rw[1][0] = *(const float4*)(W1 + (size_t)n1 * K + k0 + k8_0);
            rw[1][1] = *(const float4*)(W1 + (size_t)n1 * K + k0 + k8_0 + 4);
        } else { rw[1][0] = *(const float4*)zero4; rw[1][1] = *(const float4*)zero4; }
    };

    load_tiles(0);
    floatx4 acc0[2][2] = {};
    floatx4 acc1[2][2] = {};

    for (int k0 = 0; k0 < K; k0 += 64) {
#pragma unroll
        for (int p = 0; p < 2; ++p) {
            const int row = p ? row1 : row0;
            float v[8];
            *(float4*)&v[0] = rx[p][0]; *(float4*)&v[4] = rx[p][1];
            half8 hi, lo;
#pragma unroll
            for (int j = 0; j < 8; ++j) {
                hi[j] = (_Float16)v[j];
                lo[j] = (_Float16)((v[j] - (float)hi[j]) * 4096.0f);
            }
            *(half8*)&As[0][row][k8_0] = hi;
            *(half8*)&As[1][row][k8_0] = lo;

            *(float4*)&v[0] = rw[p][0]; *(float4*)&v[4] = rw[p][1];
#pragma unroll
            for (int j = 0; j < 8; ++j) {
                hi[j] = (_Float16)v[j];
                lo[j] = (_Float16)((v[j] - (float)hi[j]) * 4096.0f);
            }
            *(half8*)&Bs[0][row][k8_0] = hi;
            *(half8*)&Bs[1][row][k8_0] = lo;
        }
        __syncthreads();
        if (k0 + 64 < K) load_tiles(k0 + 64);

#pragma unroll
        for (int c = 0; c < 2; ++c) {
            half8 ahi[2], alo[2], bhi[2], blo[2];
#pragma unroll
            for (int mt = 0; mt < 2; ++mt) {
                ahi[mt] = *(const half8*)&As[0][wm + mt * 16 + fr][c * 32 + fq * 8];
                alo[mt] = *(const half8*)&As[1][wm + mt * 16 + fr][c * 32 + fq * 8];
            }
#pragma unroll
            for (int nt = 0; nt < 2; ++nt) {
                bhi[nt] = *(const half8*)&Bs[0][wn + nt * 16 + fr][c * 32 + fq * 8];
                blo[nt] = *(const half8*)&Bs[1][wn + nt * 16 + fr][c * 32 + fq * 8];
            }
#pragma unroll
            for (int mt = 0; mt < 2; ++mt)
#pragma unroll
                for (int nt = 0; nt < 2; ++nt) {
                    acc0[mt][nt] = __builtin_amdgcn_mfma_f32_16x16x32_f16(ahi[mt], bhi[nt], acc0[mt][nt], 0, 0, 0);
                    acc1[mt][nt] = __builtin_amdgcn_mfma_f32_16x16x32_f16(ahi[mt], blo[nt], acc1[mt][nt], 0, 0, 0);
                    acc1[mt][nt] = __builtin_amdgcn_mfma_f32_16x16x32_f16(alo[mt], bhi[nt], acc1[mt][nt], 0, 0, 0);
                }
        }
        __syncthreads();
    }

#pragma unroll
    for (int nt = 0; nt < 2; ++nt) {
        const int n = bn + wn + nt * 16 + fr;
        if (n >= Hn) continue;
        const float bias = b1[n];
#pragma unroll
        for (int mt = 0; mt < 2; ++mt) {
            const int m = bm + wm + mt * 16 + fq * 4;
#pragma unroll
            for (int r = 0; r < 4; ++r)
                H1[(size_t)(m + r) * Hn + n] =
                    acc0[mt][nt][r] + acc1[mt][nt][r] * (1.0f / 4096.0f) + bias;
        }
    }
}

// ---------------------------------------------------------------------------
// LIF scan, barrier-light (r4 version, verified).
// ---------------------------------------------------------------------------
__global__ __launch_bounds__(1024)
void snn_scan(const float* __restrict__ H1, const float* __restrict__ W2,
              const float* __restrict__ b2, float* __restrict__ out)
{
    const int b = blockIdx.x;
    const int tid = threadIdx.x;
    const int lane = tid & 63;
    const int wid = tid >> 6;
    const bool act = (tid < Hn);

    __shared__ float w2s[1024][5];
    __shared__ unsigned smask[1024];
    __shared__ float h2s[Tn][An];

#pragma unroll
    for (int a = 0; a < An; ++a)
        w2s[tid][a] = act ? W2[a * Hn + tid] : 0.f;

    float cur[Tn];
#pragma unroll
    for (int t = 0; t < Tn; ++t)
        cur[t] = act ? H1[((size_t)b * Tn + t) * Hn + tid] : 0.f;

    unsigned mask = 0;
    float mem1 = 0.f;
#pragma unroll
    for (int t = 0; t < Tn; ++t) {
        const float reset = (mem1 > 1.0f) ? 1.0f : 0.0f;
        mem1 = (0.99f * mem1 + cur[t]) * (1.0f - reset);
        if (mem1 > 1.0f) mask |= (1u << t);
    }
    smask[tid] = mask;
    __syncthreads();

#pragma unroll
    for (int tt = 0; tt < 2; ++tt) {
        const int t = wid * 2 + tt;
        float p[An] = {0.f, 0.f, 0.f, 0.f};
        for (int h = lane; h < 1024; h += 64) {
            const float g = (smask[h] >> t) & 1u ? 1.0f : 0.0f;
#pragma unroll
            for (int a = 0; a < An; ++a) p[a] += g * w2s[h][a];
        }
#pragma unroll
        for (int off = 32; off > 0; off >>= 1)
#pragma unroll
            for (int a = 0; a < An; ++a) p[a] += __shfl_down(p[a], off, 64);
        if (lane == 0) {
#pragma unroll
            for (int a = 0; a < An; ++a) h2s[t][a] = p[a];
        }
    }
    __syncthreads();

    if (tid < An) {
        const float bias = b2[tid];
        float mem2 = 0.f;
#pragma unroll
        for (int t = 0; t < Tn; ++t) {
            const float h2 = h2s[t][tid] + bias;
            const float reset = (mem2 > 1.0f) ? 1.0f : 0.0f;
            mem2 = (0.99f * mem2 + h2) * (1.0f - reset);
            out[((size_t)b * Tn + t) * An + tid] = (mem2 > 1.0f) ? 1.0f : 0.0f;
        }
    }
}

extern "C" void kernel_launch(void* const* d_in, const int* in_sizes, int n_in,
                              void* d_out, int out_size, void* d_ws, size_t ws_size,
                              hipStream_t stream) {
    const float* x  = (const float*)d_in[0];   // [B,T,D]
    const float* W1 = (const float*)d_in[1];   // [H,D]
    const float* b1 = (const float*)d_in[2];   // [H]
    const float* W2 = (const float*)d_in[3];   // [A,H]
    const float* b2 = (const float*)d_in[4];   // [A]
    float* out = (float*)d_out;                // [B,T,A]

    char* ws = (char*)d_ws;
    float* H1 = (float*)ws;

    if (ws_size >= WS_NEEDED) {
        _Float16* Xh = (_Float16*)(ws + H1_BYTES);
        _Float16* Xl = (_Float16*)(ws + H1_BYTES + XS_BYTES);
        _Float16* Wh = (_Float16*)(ws + H1_BYTES + 2 * XS_BYTES);
        _Float16* Wl = (_Float16*)(ws + H1_BYTES + 2 * XS_BYTES + WSp_BYTES);

        constexpr size_t n8 = ((size_t)Mn * Dn + (size_t)Npad * Dn) / 8;   // 4,096,000
        cvt_frag<<<(unsigned)((n8 + 255) / 256), 256, 0, stream>>>(x, W1, Xh, Xl, Wh, Wl);

        gemm_frag<<<256, 256, 0, stream>>>(Xh, Xl, Wh, Wl, b1, H1);       // bid: n=&7, m=>>3
    } else {
        dim3 grid(Mn / 64, (Hn + 63) / 64);
        gemm_fb<<<grid, 256, 0, stream>>>(x, W1, b1, H1);
    }
    snn_scan<<<Bn, 1024, 0, stream>>>(H1, W2, b2, out);
}